// Round 2
// baseline (655.348 us; speedup 1.0000x reference)
//
#include <hip/hip_runtime.h>
#include <math.h>

#define JOINTS 23
#define BATCH 16

// ---------------------------------------------------------------------------
// Kernel 1: kinematic chain -> per-joint 3x4 affine matrices A (23*12 floats)
// Single block of 64 threads (one wave). Per-joint Rodrigues in parallel,
// tree composition by depth level (max depth 5) through LDS.
// ---------------------------------------------------------------------------
__global__ void chain_kernel(const float* __restrict__ joints,
                             const float* __restrict__ j0p,
                             const float* __restrict__ j2p,
                             const float* __restrict__ j3p,
                             const float* __restrict__ j4p,
                             const float* __restrict__ j5p,
                             float* __restrict__ Aout) {
    __shared__ float sJ[JOINTS * 3];   // joint rest positions
    __shared__ float sM[JOINTS * 12];  // local mats (3x4)
    __shared__ float sC[JOINTS * 12];  // chain mats (3x4)

    const int par[JOINTS]   = {-1,0,1,1,3,4,5,4,7,4,9,1,11,12,13,12,15,12,17,0,19,0,21};
    const int depth[JOINTS] = { 0,1,2,2,3,4,5,4,5,4,5,2, 3, 4, 5, 4, 5, 4, 5,1, 2,1, 2};

    int t = threadIdx.x;
    // FIX: JOINTS*3 = 69 > 64 threads -> must loop, not single guarded load
    for (int i = t; i < JOINTS * 3; i += 64) sJ[i] = joints[i];
    __syncthreads();

    if (t < JOINTS) {
        const float hp = 1.5707963267948966f;
        float px = 0.f, py = 0.f, pz = 0.f;
        if (t == 0)       { px = j0p[0];             py = j0p[1];             pz = j0p[2]; }
        else if (t == 3)  { px = hp * tanhf(j2p[0]); py = hp * tanhf(j2p[1]); pz = hp * tanhf(j2p[2]); }
        else if (t == 4)  { px = hp * tanhf(j3p[0]); py = hp * tanhf(j3p[1]); pz = hp * tanhf(j3p[2]); }
        else if (t == 11) { px = hp * tanhf(j4p[0]); py = hp * tanhf(j4p[1]); pz = hp * tanhf(j4p[2]); }
        else if (t == 12) { px = hp * tanhf(j5p[0]); py = hp * tanhf(j5p[1]); pz = hp * tanhf(j5p[2]); }

        float ang = sqrtf(px * px + py * py + pz * pz) + 1e-8f;
        float ax = px / ang, ay = py / ang, az = pz / ang;
        float s = sinf(ang), c = cosf(ang), oc = 1.f - c;

        float R00 = 1.f + oc * (-(ay * ay + az * az));
        float R01 = -s * az + oc * ax * ay;
        float R02 =  s * ay + oc * ax * az;
        float R10 =  s * az + oc * ax * ay;
        float R11 = 1.f + oc * (-(ax * ax + az * az));
        float R12 = -s * ax + oc * ay * az;
        float R20 = -s * ay + oc * ax * az;
        float R21 =  s * ax + oc * ay * az;
        float R22 = 1.f + oc * (-(ax * ax + ay * ay));

        float rx, ry, rz;
        if (t == 0) { rx = sJ[0]; ry = sJ[1]; rz = sJ[2]; }
        else {
            int p = par[t];
            rx = sJ[t * 3 + 0] - sJ[p * 3 + 0];
            ry = sJ[t * 3 + 1] - sJ[p * 3 + 1];
            rz = sJ[t * 3 + 2] - sJ[p * 3 + 2];
        }
        float* M = &sM[t * 12];
        M[0] = R00; M[1] = R01; M[2]  = R02; M[3]  = rx;
        M[4] = R10; M[5] = R11; M[6]  = R12; M[7]  = ry;
        M[8] = R20; M[9] = R21; M[10] = R22; M[11] = rz;
    }
    __syncthreads();
    if (t == 0) {
        for (int k = 0; k < 12; k++) sC[k] = sM[k];
    }
    __syncthreads();
    for (int d = 1; d <= 5; d++) {
        if (t < JOINTS && depth[t] == d) {
            const float* C = &sC[par[t] * 12];
            const float* M = &sM[t * 12];
            float* D = &sC[t * 12];
            #pragma unroll
            for (int r = 0; r < 3; r++) {
                float c0 = C[r * 4 + 0], c1 = C[r * 4 + 1], c2 = C[r * 4 + 2], c3 = C[r * 4 + 3];
                D[r * 4 + 0] = c0 * M[0] + c1 * M[4] + c2 * M[8];
                D[r * 4 + 1] = c0 * M[1] + c1 * M[5] + c2 * M[9];
                D[r * 4 + 2] = c0 * M[2] + c1 * M[6] + c2 * M[10];
                D[r * 4 + 3] = c0 * M[3] + c1 * M[7] + c2 * M[11] + c3;
            }
        }
        __syncthreads();
    }
    if (t < JOINTS) {
        const float* C = &sC[t * 12];
        float jx = sJ[t * 3 + 0], jy = sJ[t * 3 + 1], jz = sJ[t * 3 + 2];
        #pragma unroll
        for (int r = 0; r < 3; r++) {
            float c0 = C[r * 4 + 0], c1 = C[r * 4 + 1], c2 = C[r * 4 + 2];
            float corr = c0 * jx + c1 * jy + c2 * jz;
            Aout[t * 12 + r * 4 + 0] = c0;
            Aout[t * 12 + r * 4 + 1] = c1;
            Aout[t * 12 + r * 4 + 2] = c2;
            Aout[t * 12 + r * 4 + 3] = C[r * 4 + 3] - corr;
        }
    }
}

// ---------------------------------------------------------------------------
// Kernel 2: per-vertex LBS blend + write all BATCH output copies.
// 256 vertices per block. Skin tile staged into LDS with coalesced float4
// loads (per-thread stride-23 global reads are not vector-alignable).
// ---------------------------------------------------------------------------
__global__ void __launch_bounds__(256) skin_kernel(
        const float* __restrict__ vertices,
        const float* __restrict__ skin,
        const float* __restrict__ A,
        const float* __restrict__ disp,
        const float* __restrict__ rdis,
        float* __restrict__ out,
        int V) {
    __shared__ float sA[JOINTS * 12];
    __shared__ float sS[256 * JOINTS];
    __shared__ float sV[256 * 3];

    int tid = threadIdx.x;
    int v0 = blockIdx.x * 256;
    int nv = V - v0; if (nv > 256) nv = 256;

    // FIX: JOINTS*12 = 276 > 256 threads -> must loop, not single guarded load
    for (int i = tid; i < JOINTS * 12; i += 256) sA[i] = A[i];

    int total = nv * JOINTS;
    const float* src = skin + (size_t)v0 * JOINTS;
    int n4 = total >> 2;
    const float4* src4 = (const float4*)src;
    for (int i = tid; i < n4; i += 256) ((float4*)sS)[i] = src4[i];
    for (int i = (n4 << 2) + tid; i < total; i += 256) sS[i] = src[i];
    __syncthreads();

    if (tid < nv) {
        int v = v0 + tid;
        float T[12];
        #pragma unroll
        for (int k = 0; k < 12; k++) T[k] = 0.f;
        #pragma unroll
        for (int j = 0; j < JOINTS; j++) {
            float w = sS[tid * JOINTS + j];
            #pragma unroll
            for (int k = 0; k < 12; k++) T[k] += w * sA[j * 12 + k];
        }
        float x = vertices[v * 3 + 0];
        float y = vertices[v * 3 + 1];
        float z = vertices[v * 3 + 2];
        float a0 = rdis[0] + disp[0];
        float a1 = rdis[1] + disp[1];
        float a2 = rdis[2] + disp[2];
        sV[tid * 3 + 0] = T[0] * x + T[1] * y + T[2]  * z + T[3]  + a0;
        sV[tid * 3 + 1] = T[4] * x + T[5] * y + T[6]  * z + T[7]  + a1;
        sV[tid * 3 + 2] = T[8] * x + T[9] * y + T[10] * z + T[11] + a2;
    }
    __syncthreads();

    int nf = nv * 3;
    int nf4 = nf >> 2;
    #pragma unroll
    for (int b = 0; b < BATCH; b++) {
        float* dst = out + (size_t)b * V * 3 + (size_t)v0 * 3;
        for (int i = tid; i < nf4; i += 256) ((float4*)dst)[i] = ((const float4*)sV)[i];
        for (int i = (nf4 << 2) + tid; i < nf; i += 256) dst[i] = sV[i];
    }
}

// ---------------------------------------------------------------------------
// Kernel 3: face scatter -> neighbor sums + degrees (float atomics).
// Per face: nsum[vi] += sum of the other two vertices; deg[vi] += 2.
// ---------------------------------------------------------------------------
__global__ void scatter_kernel(const int* __restrict__ faces,
                               const float* __restrict__ verts,
                               float* __restrict__ nsum,
                               float* __restrict__ deg,
                               int F) {
    int f = blockIdx.x * blockDim.x + threadIdx.x;
    if (f >= F) return;
    int a = faces[f * 3 + 0];
    int b = faces[f * 3 + 1];
    int c = faces[f * 3 + 2];
    float ax = verts[a * 3 + 0], ay = verts[a * 3 + 1], az = verts[a * 3 + 2];
    float bx = verts[b * 3 + 0], by = verts[b * 3 + 1], bz = verts[b * 3 + 2];
    float cx = verts[c * 3 + 0], cy = verts[c * 3 + 1], cz = verts[c * 3 + 2];
    atomicAdd(&nsum[a * 3 + 0], bx + cx);
    atomicAdd(&nsum[a * 3 + 1], by + cy);
    atomicAdd(&nsum[a * 3 + 2], bz + cz);
    atomicAdd(&nsum[b * 3 + 0], ax + cx);
    atomicAdd(&nsum[b * 3 + 1], ay + cy);
    atomicAdd(&nsum[b * 3 + 2], az + cz);
    atomicAdd(&nsum[c * 3 + 0], ax + bx);
    atomicAdd(&nsum[c * 3 + 1], ay + by);
    atomicAdd(&nsum[c * 3 + 2], az + bz);
    atomicAdd(&deg[a], 2.f);
    atomicAdd(&deg[b], 2.f);
    atomicAdd(&deg[c], 2.f);
}

// ---------------------------------------------------------------------------
// Kernel 4: laplacian energy reduction -> scalar at out[B*V*3]
// ---------------------------------------------------------------------------
__global__ void lap_kernel(const float* __restrict__ verts,
                           const float* __restrict__ nsum,
                           const float* __restrict__ deg,
                           float* __restrict__ lap,
                           int V) {
    int v = blockIdx.x * blockDim.x + threadIdx.x;
    float acc = 0.f;
    if (v < V) {
        float d = deg[v];
        if (d < 1.f) d = 1.f;
        float inv = 1.f / d;
        float lx = verts[v * 3 + 0] - nsum[v * 3 + 0] * inv;
        float ly = verts[v * 3 + 1] - nsum[v * 3 + 1] * inv;
        float lz = verts[v * 3 + 2] - nsum[v * 3 + 2] * inv;
        acc = lx * lx + ly * ly + lz * lz;
    }
    #pragma unroll
    for (int off = 32; off > 0; off >>= 1) acc += __shfl_down(acc, off, 64);
    __shared__ float partial[4];
    int lane = threadIdx.x & 63;
    int wid = threadIdx.x >> 6;
    if (lane == 0) partial[wid] = acc;
    __syncthreads();
    if (threadIdx.x == 0) {
        float s = partial[0] + partial[1] + partial[2] + partial[3];
        atomicAdd(lap, s);
    }
}

extern "C" void kernel_launch(void* const* d_in, const int* in_sizes, int n_in,
                              void* d_out, int out_size, void* d_ws, size_t ws_size,
                              hipStream_t stream) {
    const float* vertices = (const float*)d_in[0];
    const float* joints   = (const float*)d_in[1];
    const float* skin     = (const float*)d_in[2];
    const float* j0p      = (const float*)d_in[3];
    const float* j2p      = (const float*)d_in[4];
    const float* j3p      = (const float*)d_in[5];
    const float* j4p      = (const float*)d_in[6];
    const float* j5p      = (const float*)d_in[7];
    const float* disp     = (const float*)d_in[8];
    const float* rdis     = (const float*)d_in[9];
    const int*   faces    = (const int*)d_in[10];
    float* out = (float*)d_out;

    int V = in_sizes[0] / 3;
    int F = in_sizes[10] / 3;

    char* ws = (char*)d_ws;
    float* A    = (float*)ws;                                  // 276 floats
    float* nsum = (float*)(ws + 4096);                         // V*3 floats
    float* deg  = (float*)(ws + 4096 + (size_t)V * 3 * 4);     // V floats (contiguous after nsum)

    // zero nsum+deg (contiguous V*4 floats) and lap slot
    hipMemsetAsync(nsum, 0, (size_t)V * 16, stream);
    float* lap = out + (size_t)BATCH * V * 3;
    hipMemsetAsync(lap, 0, 4, stream);

    chain_kernel<<<1, 64, 0, stream>>>(joints, j0p, j2p, j3p, j4p, j5p, A);

    int nb = (V + 255) / 256;
    skin_kernel<<<nb, 256, 0, stream>>>(vertices, skin, A, disp, rdis, out, V);

    scatter_kernel<<<(F + 255) / 256, 256, 0, stream>>>(faces, out, nsum, deg, F);

    lap_kernel<<<nb, 256, 0, stream>>>(out, nsum, deg, lap, V);
}

// Round 3
// 400.603 us; speedup vs baseline: 1.6359x; 1.6359x over previous
//
#include <hip/hip_runtime.h>
#include <math.h>

#define JOINTS 23
#define BATCH 16

// Fixed-point packing for XCD-local atomic accumulation:
//  lane value = round(val * SCALE) + BIAS  (non-negative, < 2^21)
//  per-vertex sums < 2^28 -> no carry between packed 32-bit lanes of an int64.
#define FP_SCALE 4096.0f
#define FP_INV_SCALE (1.0f / 4096.0f)
#define FP_BIAS (1 << 20)

// ---------------------------------------------------------------------------
// Kernel 1: kinematic chain -> per-joint 3x4 affine matrices A (23*12 floats)
// ---------------------------------------------------------------------------
__global__ void chain_kernel(const float* __restrict__ joints,
                             const float* __restrict__ j0p,
                             const float* __restrict__ j2p,
                             const float* __restrict__ j3p,
                             const float* __restrict__ j4p,
                             const float* __restrict__ j5p,
                             float* __restrict__ Aout) {
    __shared__ float sJ[JOINTS * 3];
    __shared__ float sM[JOINTS * 12];
    __shared__ float sC[JOINTS * 12];

    const int par[JOINTS]   = {-1,0,1,1,3,4,5,4,7,4,9,1,11,12,13,12,15,12,17,0,19,0,21};
    const int depth[JOINTS] = { 0,1,2,2,3,4,5,4,5,4,5,2, 3, 4, 5, 4, 5, 4, 5,1, 2,1, 2};

    int t = threadIdx.x;
    for (int i = t; i < JOINTS * 3; i += 64) sJ[i] = joints[i];
    __syncthreads();

    if (t < JOINTS) {
        const float hp = 1.5707963267948966f;
        float px = 0.f, py = 0.f, pz = 0.f;
        if (t == 0)       { px = j0p[0];             py = j0p[1];             pz = j0p[2]; }
        else if (t == 3)  { px = hp * tanhf(j2p[0]); py = hp * tanhf(j2p[1]); pz = hp * tanhf(j2p[2]); }
        else if (t == 4)  { px = hp * tanhf(j3p[0]); py = hp * tanhf(j3p[1]); pz = hp * tanhf(j3p[2]); }
        else if (t == 11) { px = hp * tanhf(j4p[0]); py = hp * tanhf(j4p[1]); pz = hp * tanhf(j4p[2]); }
        else if (t == 12) { px = hp * tanhf(j5p[0]); py = hp * tanhf(j5p[1]); pz = hp * tanhf(j5p[2]); }

        float ang = sqrtf(px * px + py * py + pz * pz) + 1e-8f;
        float ax = px / ang, ay = py / ang, az = pz / ang;
        float s = sinf(ang), c = cosf(ang), oc = 1.f - c;

        float R00 = 1.f + oc * (-(ay * ay + az * az));
        float R01 = -s * az + oc * ax * ay;
        float R02 =  s * ay + oc * ax * az;
        float R10 =  s * az + oc * ax * ay;
        float R11 = 1.f + oc * (-(ax * ax + az * az));
        float R12 = -s * ax + oc * ay * az;
        float R20 = -s * ay + oc * ax * az;
        float R21 =  s * ax + oc * ay * az;
        float R22 = 1.f + oc * (-(ax * ax + ay * ay));

        float rx, ry, rz;
        if (t == 0) { rx = sJ[0]; ry = sJ[1]; rz = sJ[2]; }
        else {
            int p = par[t];
            rx = sJ[t * 3 + 0] - sJ[p * 3 + 0];
            ry = sJ[t * 3 + 1] - sJ[p * 3 + 1];
            rz = sJ[t * 3 + 2] - sJ[p * 3 + 2];
        }
        float* M = &sM[t * 12];
        M[0] = R00; M[1] = R01; M[2]  = R02; M[3]  = rx;
        M[4] = R10; M[5] = R11; M[6]  = R12; M[7]  = ry;
        M[8] = R20; M[9] = R21; M[10] = R22; M[11] = rz;
    }
    __syncthreads();
    if (t == 0) {
        for (int k = 0; k < 12; k++) sC[k] = sM[k];
    }
    __syncthreads();
    for (int d = 1; d <= 5; d++) {
        if (t < JOINTS && depth[t] == d) {
            const float* C = &sC[par[t] * 12];
            const float* M = &sM[t * 12];
            float* D = &sC[t * 12];
            #pragma unroll
            for (int r = 0; r < 3; r++) {
                float c0 = C[r * 4 + 0], c1 = C[r * 4 + 1], c2 = C[r * 4 + 2], c3 = C[r * 4 + 3];
                D[r * 4 + 0] = c0 * M[0] + c1 * M[4] + c2 * M[8];
                D[r * 4 + 1] = c0 * M[1] + c1 * M[5] + c2 * M[9];
                D[r * 4 + 2] = c0 * M[2] + c1 * M[6] + c2 * M[10];
                D[r * 4 + 3] = c0 * M[3] + c1 * M[7] + c2 * M[11] + c3;
            }
        }
        __syncthreads();
    }
    if (t < JOINTS) {
        const float* C = &sC[t * 12];
        float jx = sJ[t * 3 + 0], jy = sJ[t * 3 + 1], jz = sJ[t * 3 + 2];
        #pragma unroll
        for (int r = 0; r < 3; r++) {
            float c0 = C[r * 4 + 0], c1 = C[r * 4 + 1], c2 = C[r * 4 + 2];
            float corr = c0 * jx + c1 * jy + c2 * jz;
            Aout[t * 12 + r * 4 + 0] = c0;
            Aout[t * 12 + r * 4 + 1] = c1;
            Aout[t * 12 + r * 4 + 2] = c2;
            Aout[t * 12 + r * 4 + 3] = C[r * 4 + 3] - corr;
        }
    }
}

// ---------------------------------------------------------------------------
// Kernel 2: per-vertex LBS blend + write all BATCH output copies.
// ---------------------------------------------------------------------------
__global__ void __launch_bounds__(256) skin_kernel(
        const float* __restrict__ vertices,
        const float* __restrict__ skin,
        const float* __restrict__ A,
        const float* __restrict__ disp,
        const float* __restrict__ rdis,
        float* __restrict__ out,
        int V) {
    __shared__ float sA[JOINTS * 12];
    __shared__ float sS[256 * JOINTS];
    __shared__ float sV[256 * 3];

    int tid = threadIdx.x;
    int v0 = blockIdx.x * 256;
    int nv = V - v0; if (nv > 256) nv = 256;

    for (int i = tid; i < JOINTS * 12; i += 256) sA[i] = A[i];

    int total = nv * JOINTS;
    const float* src = skin + (size_t)v0 * JOINTS;
    int n4 = total >> 2;
    const float4* src4 = (const float4*)src;
    for (int i = tid; i < n4; i += 256) ((float4*)sS)[i] = src4[i];
    for (int i = (n4 << 2) + tid; i < total; i += 256) sS[i] = src[i];
    __syncthreads();

    if (tid < nv) {
        int v = v0 + tid;
        float T[12];
        #pragma unroll
        for (int k = 0; k < 12; k++) T[k] = 0.f;
        #pragma unroll
        for (int j = 0; j < JOINTS; j++) {
            float w = sS[tid * JOINTS + j];
            #pragma unroll
            for (int k = 0; k < 12; k++) T[k] += w * sA[j * 12 + k];
        }
        float x = vertices[v * 3 + 0];
        float y = vertices[v * 3 + 1];
        float z = vertices[v * 3 + 2];
        float a0 = rdis[0] + disp[0];
        float a1 = rdis[1] + disp[1];
        float a2 = rdis[2] + disp[2];
        sV[tid * 3 + 0] = T[0] * x + T[1] * y + T[2]  * z + T[3]  + a0;
        sV[tid * 3 + 1] = T[4] * x + T[5] * y + T[6]  * z + T[7]  + a1;
        sV[tid * 3 + 2] = T[8] * x + T[9] * y + T[10] * z + T[11] + a2;
    }
    __syncthreads();

    int nf = nv * 3;
    int nf4 = nf >> 2;
    #pragma unroll
    for (int b = 0; b < BATCH; b++) {
        float* dst = out + (size_t)b * V * 3 + (size_t)v0 * 3;
        for (int i = tid; i < nf4; i += 256) ((float4*)dst)[i] = ((const float4*)sV)[i];
        for (int i = (nf4 << 2) + tid; i < nf; i += 256) dst[i] = sV[i];
    }
}

// ---------------------------------------------------------------------------
// Kernel 3 (fast path): face scatter with XCD-private buffers and
// workgroup-scope (L2-local, no sc1) int64 atomics.
// Per vertex entry: [0] = (y_lane<<32)|x_lane, [1] = (cnt<<32)|z_lane.
// ---------------------------------------------------------------------------
__device__ __forceinline__ unsigned fp_enc(float v) {
    return (unsigned)(__float2int_rn(v * FP_SCALE) + FP_BIAS);
}

__global__ void scatter_xcd_kernel(const int* __restrict__ faces,
                                   const float* __restrict__ verts,
                                   long long* __restrict__ acc,
                                   int V, int F) {
    unsigned xcc;
    asm volatile("s_getreg_b32 %0, hwreg(HW_REG_XCC_ID)" : "=s"(xcc));
    long long* base = acc + (size_t)(xcc & 7) * (size_t)V * 2;

    int f = blockIdx.x * blockDim.x + threadIdx.x;
    if (f >= F) return;
    int a = faces[f * 3 + 0];
    int b = faces[f * 3 + 1];
    int c = faces[f * 3 + 2];
    float ax = verts[a * 3 + 0], ay = verts[a * 3 + 1], az = verts[a * 3 + 2];
    float bx = verts[b * 3 + 0], by = verts[b * 3 + 1], bz = verts[b * 3 + 2];
    float cx = verts[c * 3 + 0], cy = verts[c * 3 + 1], cz = verts[c * 3 + 2];

    // corner a += (b + c)
    {
        long long A = ((long long)fp_enc(by + cy) << 32) | (long long)fp_enc(bx + cx);
        long long Bv = (1ll << 32) | (long long)fp_enc(bz + cz);
        __hip_atomic_fetch_add(&base[(size_t)a * 2 + 0], A,  __ATOMIC_RELAXED, __HIP_MEMORY_SCOPE_WORKGROUP);
        __hip_atomic_fetch_add(&base[(size_t)a * 2 + 1], Bv, __ATOMIC_RELAXED, __HIP_MEMORY_SCOPE_WORKGROUP);
    }
    // corner b += (a + c)
    {
        long long A = ((long long)fp_enc(ay + cy) << 32) | (long long)fp_enc(ax + cx);
        long long Bv = (1ll << 32) | (long long)fp_enc(az + cz);
        __hip_atomic_fetch_add(&base[(size_t)b * 2 + 0], A,  __ATOMIC_RELAXED, __HIP_MEMORY_SCOPE_WORKGROUP);
        __hip_atomic_fetch_add(&base[(size_t)b * 2 + 1], Bv, __ATOMIC_RELAXED, __HIP_MEMORY_SCOPE_WORKGROUP);
    }
    // corner c += (a + b)
    {
        long long A = ((long long)fp_enc(ay + by) << 32) | (long long)fp_enc(ax + bx);
        long long Bv = (1ll << 32) | (long long)fp_enc(az + bz);
        __hip_atomic_fetch_add(&base[(size_t)c * 2 + 0], A,  __ATOMIC_RELAXED, __HIP_MEMORY_SCOPE_WORKGROUP);
        __hip_atomic_fetch_add(&base[(size_t)c * 2 + 1], Bv, __ATOMIC_RELAXED, __HIP_MEMORY_SCOPE_WORKGROUP);
    }
}

// ---------------------------------------------------------------------------
// Kernel 4 (fast path): reduce 8 XCD buffers + laplacian energy.
// ---------------------------------------------------------------------------
__global__ void __launch_bounds__(256) lap_reduce_kernel(
        const float* __restrict__ verts,
        const longlong2* __restrict__ acc,
        float* __restrict__ lap,
        int V) {
    int v = blockIdx.x * blockDim.x + threadIdx.x;
    float e = 0.f;
    if (v < V) {
        long long xs = 0, ys = 0, zs = 0, cs = 0;
        #pragma unroll
        for (int b = 0; b < 8; b++) {
            longlong2 t = acc[(size_t)b * V + v];
            xs += (long long)(unsigned)(t.x & 0xffffffffll);
            ys += (long long)(unsigned long long)((unsigned long long)t.x >> 32);
            zs += (long long)(unsigned)(t.y & 0xffffffffll);
            cs += (long long)(unsigned long long)((unsigned long long)t.y >> 32);
        }
        float vx = verts[v * 3 + 0];
        float vy = verts[v * 3 + 1];
        float vz = verts[v * 3 + 2];
        float lx, ly, lz;
        if (cs == 0) {
            lx = vx; ly = vy; lz = vz;   // deg=0 -> max(deg,1)=1, nsum=0
        } else {
            float inv = 1.f / (2.f * (float)cs);   // deg = 2*cnt
            float nx = (float)(xs - cs * (long long)FP_BIAS) * FP_INV_SCALE;
            float ny = (float)(ys - cs * (long long)FP_BIAS) * FP_INV_SCALE;
            float nz = (float)(zs - cs * (long long)FP_BIAS) * FP_INV_SCALE;
            lx = vx - nx * inv;
            ly = vy - ny * inv;
            lz = vz - nz * inv;
        }
        e = lx * lx + ly * ly + lz * lz;
    }
    #pragma unroll
    for (int off = 32; off > 0; off >>= 1) e += __shfl_down(e, off, 64);
    __shared__ float partial[4];
    int lane = threadIdx.x & 63;
    int wid = threadIdx.x >> 6;
    if (lane == 0) partial[wid] = e;
    __syncthreads();
    if (threadIdx.x == 0) {
        float s = partial[0] + partial[1] + partial[2] + partial[3];
        atomicAdd(lap, s);
    }
}

// ---------------------------------------------------------------------------
// Fallback path (Round-2 proven): device-scope float atomics.
// ---------------------------------------------------------------------------
__global__ void scatter_kernel(const int* __restrict__ faces,
                               const float* __restrict__ verts,
                               float* __restrict__ nsum,
                               float* __restrict__ deg,
                               int F) {
    int f = blockIdx.x * blockDim.x + threadIdx.x;
    if (f >= F) return;
    int a = faces[f * 3 + 0];
    int b = faces[f * 3 + 1];
    int c = faces[f * 3 + 2];
    float ax = verts[a * 3 + 0], ay = verts[a * 3 + 1], az = verts[a * 3 + 2];
    float bx = verts[b * 3 + 0], by = verts[b * 3 + 1], bz = verts[b * 3 + 2];
    float cx = verts[c * 3 + 0], cy = verts[c * 3 + 1], cz = verts[c * 3 + 2];
    atomicAdd(&nsum[a * 3 + 0], bx + cx);
    atomicAdd(&nsum[a * 3 + 1], by + cy);
    atomicAdd(&nsum[a * 3 + 2], bz + cz);
    atomicAdd(&nsum[b * 3 + 0], ax + cx);
    atomicAdd(&nsum[b * 3 + 1], ay + cy);
    atomicAdd(&nsum[b * 3 + 2], az + cz);
    atomicAdd(&nsum[c * 3 + 0], ax + bx);
    atomicAdd(&nsum[c * 3 + 1], ay + by);
    atomicAdd(&nsum[c * 3 + 2], az + bz);
    atomicAdd(&deg[a], 2.f);
    atomicAdd(&deg[b], 2.f);
    atomicAdd(&deg[c], 2.f);
}

__global__ void lap_kernel(const float* __restrict__ verts,
                           const float* __restrict__ nsum,
                           const float* __restrict__ deg,
                           float* __restrict__ lap,
                           int V) {
    int v = blockIdx.x * blockDim.x + threadIdx.x;
    float acc = 0.f;
    if (v < V) {
        float d = deg[v];
        if (d < 1.f) d = 1.f;
        float inv = 1.f / d;
        float lx = verts[v * 3 + 0] - nsum[v * 3 + 0] * inv;
        float ly = verts[v * 3 + 1] - nsum[v * 3 + 1] * inv;
        float lz = verts[v * 3 + 2] - nsum[v * 3 + 2] * inv;
        acc = lx * lx + ly * ly + lz * lz;
    }
    #pragma unroll
    for (int off = 32; off > 0; off >>= 1) acc += __shfl_down(acc, off, 64);
    __shared__ float partial[4];
    int lane = threadIdx.x & 63;
    int wid = threadIdx.x >> 6;
    if (lane == 0) partial[wid] = acc;
    __syncthreads();
    if (threadIdx.x == 0) {
        float s = partial[0] + partial[1] + partial[2] + partial[3];
        atomicAdd(lap, s);
    }
}

extern "C" void kernel_launch(void* const* d_in, const int* in_sizes, int n_in,
                              void* d_out, int out_size, void* d_ws, size_t ws_size,
                              hipStream_t stream) {
    const float* vertices = (const float*)d_in[0];
    const float* joints   = (const float*)d_in[1];
    const float* skin     = (const float*)d_in[2];
    const float* j0p      = (const float*)d_in[3];
    const float* j2p      = (const float*)d_in[4];
    const float* j3p      = (const float*)d_in[5];
    const float* j4p      = (const float*)d_in[6];
    const float* j5p      = (const float*)d_in[7];
    const float* disp     = (const float*)d_in[8];
    const float* rdis     = (const float*)d_in[9];
    const int*   faces    = (const int*)d_in[10];
    float* out = (float*)d_out;

    int V = in_sizes[0] / 3;
    int F = in_sizes[10] / 3;

    char* ws = (char*)d_ws;
    float* A = (float*)ws;                       // 276 floats at offset 0
    float* lap = out + (size_t)BATCH * V * 3;

    size_t accBytes = (size_t)8 * (size_t)V * 16;   // 8 XCD buffers x V x 16B
    bool fast = (ws_size >= 4096 + accBytes);

    hipMemsetAsync(lap, 0, 4, stream);
    chain_kernel<<<1, 64, 0, stream>>>(joints, j0p, j2p, j3p, j4p, j5p, A);

    int nb = (V + 255) / 256;
    skin_kernel<<<nb, 256, 0, stream>>>(vertices, skin, A, disp, rdis, out, V);

    if (fast) {
        long long* acc = (long long*)(ws + 4096);
        hipMemsetAsync(acc, 0, accBytes, stream);
        scatter_xcd_kernel<<<(F + 255) / 256, 256, 0, stream>>>(faces, out, acc, V, F);
        lap_reduce_kernel<<<nb, 256, 0, stream>>>(out, (const longlong2*)acc, lap, V);
    } else {
        float* nsum = (float*)(ws + 4096);
        float* deg  = (float*)(ws + 4096 + (size_t)V * 3 * 4);
        hipMemsetAsync(nsum, 0, (size_t)V * 16, stream);
        scatter_kernel<<<(F + 255) / 256, 256, 0, stream>>>(faces, out, nsum, deg, F);
        lap_kernel<<<nb, 256, 0, stream>>>(out, nsum, deg, lap, V);
    }
}

// Round 4
// 295.463 us; speedup vs baseline: 2.2180x; 1.3559x over previous
//
#include <hip/hip_runtime.h>
#include <math.h>

#define JOINTS 23
#define BATCH 16

// u64 lane packing for one-atomic-per-corner accumulation:
//   bits [ 0,20) x-sum lane, [20,40) y-sum, [40,59) z-sum, [59,64) corner count
//   lane value per corner = round(val*128) + 4096  (val = sum of 2 coords, |.|<32)
//   per-vertex corner count <= ~24 -> lane sums < 2^18, no inter-lane carry.
#define FPS 128.0f
#define FPS_INV (1.0f / 128.0f)
#define FPB 4096

// ---------------------------------------------------------------------------
// Kernel 1: kinematic chain -> per-joint 3x4 affine matrices A (23*12 floats)
// ---------------------------------------------------------------------------
__global__ void chain_kernel(const float* __restrict__ joints,
                             const float* __restrict__ j0p,
                             const float* __restrict__ j2p,
                             const float* __restrict__ j3p,
                             const float* __restrict__ j4p,
                             const float* __restrict__ j5p,
                             float* __restrict__ Aout) {
    __shared__ float sJ[JOINTS * 3];
    __shared__ float sM[JOINTS * 12];
    __shared__ float sC[JOINTS * 12];

    const int par[JOINTS]   = {-1,0,1,1,3,4,5,4,7,4,9,1,11,12,13,12,15,12,17,0,19,0,21};
    const int depth[JOINTS] = { 0,1,2,2,3,4,5,4,5,4,5,2, 3, 4, 5, 4, 5, 4, 5,1, 2,1, 2};

    int t = threadIdx.x;
    for (int i = t; i < JOINTS * 3; i += 64) sJ[i] = joints[i];
    __syncthreads();

    if (t < JOINTS) {
        const float hp = 1.5707963267948966f;
        float px = 0.f, py = 0.f, pz = 0.f;
        if (t == 0)       { px = j0p[0];             py = j0p[1];             pz = j0p[2]; }
        else if (t == 3)  { px = hp * tanhf(j2p[0]); py = hp * tanhf(j2p[1]); pz = hp * tanhf(j2p[2]); }
        else if (t == 4)  { px = hp * tanhf(j3p[0]); py = hp * tanhf(j3p[1]); pz = hp * tanhf(j3p[2]); }
        else if (t == 11) { px = hp * tanhf(j4p[0]); py = hp * tanhf(j4p[1]); pz = hp * tanhf(j4p[2]); }
        else if (t == 12) { px = hp * tanhf(j5p[0]); py = hp * tanhf(j5p[1]); pz = hp * tanhf(j5p[2]); }

        float ang = sqrtf(px * px + py * py + pz * pz) + 1e-8f;
        float ax = px / ang, ay = py / ang, az = pz / ang;
        float s = sinf(ang), c = cosf(ang), oc = 1.f - c;

        float R00 = 1.f + oc * (-(ay * ay + az * az));
        float R01 = -s * az + oc * ax * ay;
        float R02 =  s * ay + oc * ax * az;
        float R10 =  s * az + oc * ax * ay;
        float R11 = 1.f + oc * (-(ax * ax + az * az));
        float R12 = -s * ax + oc * ay * az;
        float R20 = -s * ay + oc * ax * az;
        float R21 =  s * ax + oc * ay * az;
        float R22 = 1.f + oc * (-(ax * ax + ay * ay));

        float rx, ry, rz;
        if (t == 0) { rx = sJ[0]; ry = sJ[1]; rz = sJ[2]; }
        else {
            int p = par[t];
            rx = sJ[t * 3 + 0] - sJ[p * 3 + 0];
            ry = sJ[t * 3 + 1] - sJ[p * 3 + 1];
            rz = sJ[t * 3 + 2] - sJ[p * 3 + 2];
        }
        float* M = &sM[t * 12];
        M[0] = R00; M[1] = R01; M[2]  = R02; M[3]  = rx;
        M[4] = R10; M[5] = R11; M[6]  = R12; M[7]  = ry;
        M[8] = R20; M[9] = R21; M[10] = R22; M[11] = rz;
    }
    __syncthreads();
    if (t == 0) {
        for (int k = 0; k < 12; k++) sC[k] = sM[k];
    }
    __syncthreads();
    for (int d = 1; d <= 5; d++) {
        if (t < JOINTS && depth[t] == d) {
            const float* C = &sC[par[t] * 12];
            const float* M = &sM[t * 12];
            float* D = &sC[t * 12];
            #pragma unroll
            for (int r = 0; r < 3; r++) {
                float c0 = C[r * 4 + 0], c1 = C[r * 4 + 1], c2 = C[r * 4 + 2], c3 = C[r * 4 + 3];
                D[r * 4 + 0] = c0 * M[0] + c1 * M[4] + c2 * M[8];
                D[r * 4 + 1] = c0 * M[1] + c1 * M[5] + c2 * M[9];
                D[r * 4 + 2] = c0 * M[2] + c1 * M[6] + c2 * M[10];
                D[r * 4 + 3] = c0 * M[3] + c1 * M[7] + c2 * M[11] + c3;
            }
        }
        __syncthreads();
    }
    if (t < JOINTS) {
        const float* C = &sC[t * 12];
        float jx = sJ[t * 3 + 0], jy = sJ[t * 3 + 1], jz = sJ[t * 3 + 2];
        #pragma unroll
        for (int r = 0; r < 3; r++) {
            float c0 = C[r * 4 + 0], c1 = C[r * 4 + 1], c2 = C[r * 4 + 2];
            float corr = c0 * jx + c1 * jy + c2 * jz;
            Aout[t * 12 + r * 4 + 0] = c0;
            Aout[t * 12 + r * 4 + 1] = c1;
            Aout[t * 12 + r * 4 + 2] = c2;
            Aout[t * 12 + r * 4 + 3] = C[r * 4 + 3] - corr;
        }
    }
}

// ---------------------------------------------------------------------------
// Kernel 2: per-vertex LBS blend + write all BATCH output copies.
// ---------------------------------------------------------------------------
__global__ void __launch_bounds__(256) skin_kernel(
        const float* __restrict__ vertices,
        const float* __restrict__ skin,
        const float* __restrict__ A,
        const float* __restrict__ disp,
        const float* __restrict__ rdis,
        float* __restrict__ out,
        int V) {
    __shared__ float sA[JOINTS * 12];
    __shared__ float sS[256 * JOINTS];
    __shared__ float sV[256 * 3];

    int tid = threadIdx.x;
    int v0 = blockIdx.x * 256;
    int nv = V - v0; if (nv > 256) nv = 256;

    for (int i = tid; i < JOINTS * 12; i += 256) sA[i] = A[i];

    int total = nv * JOINTS;
    const float* src = skin + (size_t)v0 * JOINTS;
    int n4 = total >> 2;
    const float4* src4 = (const float4*)src;
    for (int i = tid; i < n4; i += 256) ((float4*)sS)[i] = src4[i];
    for (int i = (n4 << 2) + tid; i < total; i += 256) sS[i] = src[i];
    __syncthreads();

    if (tid < nv) {
        int v = v0 + tid;
        float T[12];
        #pragma unroll
        for (int k = 0; k < 12; k++) T[k] = 0.f;
        #pragma unroll
        for (int j = 0; j < JOINTS; j++) {
            float w = sS[tid * JOINTS + j];
            #pragma unroll
            for (int k = 0; k < 12; k++) T[k] += w * sA[j * 12 + k];
        }
        float x = vertices[v * 3 + 0];
        float y = vertices[v * 3 + 1];
        float z = vertices[v * 3 + 2];
        float a0 = rdis[0] + disp[0];
        float a1 = rdis[1] + disp[1];
        float a2 = rdis[2] + disp[2];
        sV[tid * 3 + 0] = T[0] * x + T[1] * y + T[2]  * z + T[3]  + a0;
        sV[tid * 3 + 1] = T[4] * x + T[5] * y + T[6]  * z + T[7]  + a1;
        sV[tid * 3 + 2] = T[8] * x + T[9] * y + T[10] * z + T[11] + a2;
    }
    __syncthreads();

    int nf = nv * 3;
    int nf4 = nf >> 2;
    #pragma unroll
    for (int b = 0; b < BATCH; b++) {
        float* dst = out + (size_t)b * V * 3 + (size_t)v0 * 3;
        for (int i = tid; i < nf4; i += 256) ((float4*)dst)[i] = ((const float4*)sV)[i];
        for (int i = (nf4 << 2) + tid; i < nf; i += 256) dst[i] = sV[i];
    }
}

// ---------------------------------------------------------------------------
// Kernel 3 (fast path): face scatter, XCD-private buffers, ONE u64
// workgroup-scope (L2-local) atomic per corner. 8B/vertex/XCD -> 3.2MB/XCD,
// fits the 4MiB per-XCD L2. Faces+verts read nontemporally to keep the
// accumulator resident in L2.
// ---------------------------------------------------------------------------
__device__ __forceinline__ unsigned long long pack_corner(float sx, float sy, float sz) {
    unsigned long long ex = (unsigned)(__float2int_rn(sx * FPS) + FPB);
    unsigned long long ey = (unsigned)(__float2int_rn(sy * FPS) + FPB);
    unsigned long long ez = (unsigned)(__float2int_rn(sz * FPS) + FPB);
    return ex | (ey << 20) | (ez << 40) | (1ull << 59);
}

__global__ void __launch_bounds__(256) scatter_xcd_kernel(
        const int* __restrict__ faces,
        const float* __restrict__ verts,
        unsigned long long* __restrict__ acc,
        int V, int F) {
    unsigned xcc;
    asm volatile("s_getreg_b32 %0, hwreg(HW_REG_XCC_ID)" : "=s"(xcc));
    unsigned long long* base = acc + (size_t)(xcc & 7) * (size_t)V;

    int f = blockIdx.x * blockDim.x + threadIdx.x;
    if (f >= F) return;
    int a = __builtin_nontemporal_load(&faces[f * 3 + 0]);
    int b = __builtin_nontemporal_load(&faces[f * 3 + 1]);
    int c = __builtin_nontemporal_load(&faces[f * 3 + 2]);
    float ax = __builtin_nontemporal_load(&verts[a * 3 + 0]);
    float ay = __builtin_nontemporal_load(&verts[a * 3 + 1]);
    float az = __builtin_nontemporal_load(&verts[a * 3 + 2]);
    float bx = __builtin_nontemporal_load(&verts[b * 3 + 0]);
    float by = __builtin_nontemporal_load(&verts[b * 3 + 1]);
    float bz = __builtin_nontemporal_load(&verts[b * 3 + 2]);
    float cx = __builtin_nontemporal_load(&verts[c * 3 + 0]);
    float cy = __builtin_nontemporal_load(&verts[c * 3 + 1]);
    float cz = __builtin_nontemporal_load(&verts[c * 3 + 2]);

    unsigned long long pa = pack_corner(bx + cx, by + cy, bz + cz);
    unsigned long long pb = pack_corner(ax + cx, ay + cy, az + cz);
    unsigned long long pc = pack_corner(ax + bx, ay + by, az + bz);
    __hip_atomic_fetch_add(&base[a], pa, __ATOMIC_RELAXED, __HIP_MEMORY_SCOPE_WORKGROUP);
    __hip_atomic_fetch_add(&base[b], pb, __ATOMIC_RELAXED, __HIP_MEMORY_SCOPE_WORKGROUP);
    __hip_atomic_fetch_add(&base[c], pc, __ATOMIC_RELAXED, __HIP_MEMORY_SCOPE_WORKGROUP);
}

// ---------------------------------------------------------------------------
// Kernel 4 (fast path): reduce 8 XCD buffers (packed-sum is carry-free) +
// laplacian energy.
// ---------------------------------------------------------------------------
__global__ void __launch_bounds__(256) lap_reduce_kernel(
        const float* __restrict__ verts,
        const unsigned long long* __restrict__ acc,
        float* __restrict__ lap,
        int V) {
    int v = blockIdx.x * blockDim.x + threadIdx.x;
    float e = 0.f;
    if (v < V) {
        unsigned long long u = 0;
        #pragma unroll
        for (int b = 0; b < 8; b++) u += acc[(size_t)b * V + v];
        long long cnt = (long long)(u >> 59);
        long long zs  = (long long)((u >> 40) & 0x7FFFFull);
        long long ys  = (long long)((u >> 20) & 0xFFFFFull);
        long long xs  = (long long)(u & 0xFFFFFull);
        float vx = verts[v * 3 + 0];
        float vy = verts[v * 3 + 1];
        float vz = verts[v * 3 + 2];
        float lx, ly, lz;
        if (cnt == 0) {
            lx = vx; ly = vy; lz = vz;   // deg=0 -> max(deg,1)=1, nsum=0
        } else {
            float inv = 1.f / (2.f * (float)cnt);     // deg = 2*cnt
            float nx = (float)(xs - cnt * FPB) * FPS_INV;
            float ny = (float)(ys - cnt * FPB) * FPS_INV;
            float nz = (float)(zs - cnt * FPB) * FPS_INV;
            lx = vx - nx * inv;
            ly = vy - ny * inv;
            lz = vz - nz * inv;
        }
        e = lx * lx + ly * ly + lz * lz;
    }
    #pragma unroll
    for (int off = 32; off > 0; off >>= 1) e += __shfl_down(e, off, 64);
    __shared__ float partial[4];
    int lane = threadIdx.x & 63;
    int wid = threadIdx.x >> 6;
    if (lane == 0) partial[wid] = e;
    __syncthreads();
    if (threadIdx.x == 0) {
        float s = partial[0] + partial[1] + partial[2] + partial[3];
        atomicAdd(lap, s);
    }
}

// ---------------------------------------------------------------------------
// Fallback path (Round-2 proven): device-scope float atomics.
// ---------------------------------------------------------------------------
__global__ void scatter_kernel(const int* __restrict__ faces,
                               const float* __restrict__ verts,
                               float* __restrict__ nsum,
                               float* __restrict__ deg,
                               int F) {
    int f = blockIdx.x * blockDim.x + threadIdx.x;
    if (f >= F) return;
    int a = faces[f * 3 + 0];
    int b = faces[f * 3 + 1];
    int c = faces[f * 3 + 2];
    float ax = verts[a * 3 + 0], ay = verts[a * 3 + 1], az = verts[a * 3 + 2];
    float bx = verts[b * 3 + 0], by = verts[b * 3 + 1], bz = verts[b * 3 + 2];
    float cx = verts[c * 3 + 0], cy = verts[c * 3 + 1], cz = verts[c * 3 + 2];
    atomicAdd(&nsum[a * 3 + 0], bx + cx);
    atomicAdd(&nsum[a * 3 + 1], by + cy);
    atomicAdd(&nsum[a * 3 + 2], bz + cz);
    atomicAdd(&nsum[b * 3 + 0], ax + cx);
    atomicAdd(&nsum[b * 3 + 1], ay + cy);
    atomicAdd(&nsum[b * 3 + 2], az + cz);
    atomicAdd(&nsum[c * 3 + 0], ax + bx);
    atomicAdd(&nsum[c * 3 + 1], ay + by);
    atomicAdd(&nsum[c * 3 + 2], az + bz);
    atomicAdd(&deg[a], 2.f);
    atomicAdd(&deg[b], 2.f);
    atomicAdd(&deg[c], 2.f);
}

__global__ void lap_kernel(const float* __restrict__ verts,
                           const float* __restrict__ nsum,
                           const float* __restrict__ deg,
                           float* __restrict__ lap,
                           int V) {
    int v = blockIdx.x * blockDim.x + threadIdx.x;
    float acc = 0.f;
    if (v < V) {
        float d = deg[v];
        if (d < 1.f) d = 1.f;
        float inv = 1.f / d;
        float lx = verts[v * 3 + 0] - nsum[v * 3 + 0] * inv;
        float ly = verts[v * 3 + 1] - nsum[v * 3 + 1] * inv;
        float lz = verts[v * 3 + 2] - nsum[v * 3 + 2] * inv;
        acc = lx * lx + ly * ly + lz * lz;
    }
    #pragma unroll
    for (int off = 32; off > 0; off >>= 1) acc += __shfl_down(acc, off, 64);
    __shared__ float partial[4];
    int lane = threadIdx.x & 63;
    int wid = threadIdx.x >> 6;
    if (lane == 0) partial[wid] = acc;
    __syncthreads();
    if (threadIdx.x == 0) {
        float s = partial[0] + partial[1] + partial[2] + partial[3];
        atomicAdd(lap, s);
    }
}

extern "C" void kernel_launch(void* const* d_in, const int* in_sizes, int n_in,
                              void* d_out, int out_size, void* d_ws, size_t ws_size,
                              hipStream_t stream) {
    const float* vertices = (const float*)d_in[0];
    const float* joints   = (const float*)d_in[1];
    const float* skin     = (const float*)d_in[2];
    const float* j0p      = (const float*)d_in[3];
    const float* j2p      = (const float*)d_in[4];
    const float* j3p      = (const float*)d_in[5];
    const float* j4p      = (const float*)d_in[6];
    const float* j5p      = (const float*)d_in[7];
    const float* disp     = (const float*)d_in[8];
    const float* rdis     = (const float*)d_in[9];
    const int*   faces    = (const int*)d_in[10];
    float* out = (float*)d_out;

    int V = in_sizes[0] / 3;
    int F = in_sizes[10] / 3;

    char* ws = (char*)d_ws;
    float* A = (float*)ws;                       // 276 floats at offset 0
    float* lap = out + (size_t)BATCH * V * 3;

    size_t accBytes = (size_t)8 * (size_t)V * 8;    // 8 XCD buffers x V x 8B
    bool fast = (ws_size >= 4096 + accBytes);

    hipMemsetAsync(lap, 0, 4, stream);
    chain_kernel<<<1, 64, 0, stream>>>(joints, j0p, j2p, j3p, j4p, j5p, A);

    int nb = (V + 255) / 256;
    skin_kernel<<<nb, 256, 0, stream>>>(vertices, skin, A, disp, rdis, out, V);

    if (fast) {
        unsigned long long* acc = (unsigned long long*)(ws + 4096);
        hipMemsetAsync(acc, 0, accBytes, stream);
        scatter_xcd_kernel<<<(F + 255) / 256, 256, 0, stream>>>(faces, out, acc, V, F);
        lap_reduce_kernel<<<nb, 256, 0, stream>>>(out, acc, lap, V);
    } else {
        float* nsum = (float*)(ws + 4096);
        float* deg  = (float*)(ws + 4096 + (size_t)V * 3 * 4);
        hipMemsetAsync(nsum, 0, (size_t)V * 16, stream);
        scatter_kernel<<<(F + 255) / 256, 256, 0, stream>>>(faces, out, nsum, deg, F);
        lap_kernel<<<nb, 256, 0, stream>>>(out, nsum, deg, lap, V);
    }
}